// Round 5
// baseline (100.102 us; speedup 1.0000x reference)
//
#include <hip/hip_runtime.h>

#define BATCH  8192
#define HIST   50
#define REPR   512
#define N_EMB  100000
#define NSLICE 8
#define SLICE_SZ ((N_EMB + NSLICE - 1) / NSLICE)   // 12500 rows = 25.6 MB
#define CH     8

typedef float v4f __attribute__((ext_vector_type(4)));

// Slice-phased embedding-bag sum, single kernel.
// Each 128-thread group (one batch row; 2 groups per 256-thread block)
// counting-sorts its valid indices into NSLICE buckets in LDS, then gathers
// bucket-by-bucket. Since ~2048 blocks run roughly in lockstep, the
// chip-wide active table footprint at any instant is ~1-2 slices (26-51 MB)
// << 256 MB L3, so row reuse and re-reads hit L3 instead of churning it.
// Accumulator stays in registers; out is written once, nontemporally.
__global__ __launch_bounds__(256) void embbag_sliced_kernel(
    const int* __restrict__ target,      // [BATCH, HIST], -1 = sentinel
    const float* __restrict__ emb,       // [N_EMB, REPR]
    float* __restrict__ out)             // [BATCH, REPR]
{
    __shared__ int s_idx[2][NSLICE][HIST];   // bucketed indices, per group
    __shared__ int s_cnt[2][NSLICE];

    const int g    = threadIdx.x >> 7;       // group (batch row) within block
    const int lane = threadIdx.x & 127;      // float4 slot 0..127
    const int row  = blockIdx.x * 2 + g;

    // ---- stage 1: bucket this row's valid indices by table slice ----
    if (lane < NSLICE) s_cnt[g][lane] = 0;
    __syncthreads();
    if (lane < HIST) {
        const int ix = target[row * HIST + lane];
        if (ix >= 0) {
            const int b   = ix / SLICE_SZ;
            const int pos = atomicAdd(&s_cnt[g][b], 1);
            s_idx[g][b][pos] = ix;
        }
    }
    __syncthreads();

    // ---- stage 2: gather slice by slice, CH loads in flight ----
    const float* col = emb + (size_t)lane * 4;
    float4 acc = make_float4(0.f, 0.f, 0.f, 0.f);

    for (int p = 0; p < NSLICE; ++p) {
        const int n = s_cnt[g][p];
        for (int k0 = 0; k0 < n; k0 += CH) {
            int    idx[CH];
            float  w[CH];
            float4 v[CH];
#pragma unroll
            for (int k = 0; k < CH; ++k) {
                const bool valid = (k0 + k) < n;
                idx[k] = valid ? s_idx[g][p][k0 + k] : 0;  // uniform LDS read
                w[k]   = valid ? 1.0f : 0.0f;
            }
#pragma unroll
            for (int k = 0; k < CH; ++k) {
                v[k] = *reinterpret_cast<const float4*>(col + (size_t)idx[k] * REPR);
            }
#pragma unroll
            for (int k = 0; k < CH; ++k) {
                acc.x = fmaf(v[k].x, w[k], acc.x);
                acc.y = fmaf(v[k].y, w[k], acc.y);
                acc.z = fmaf(v[k].z, w[k], acc.z);
                acc.w = fmaf(v[k].w, w[k], acc.w);
            }
        }
    }

    v4f av;
    av.x = acc.x; av.y = acc.y; av.z = acc.z; av.w = acc.w;
    v4f* o = reinterpret_cast<v4f*>(out + (size_t)row * REPR + (size_t)lane * 4);
    __builtin_nontemporal_store(av, o);
}

extern "C" void kernel_launch(void* const* d_in, const int* in_sizes, int n_in,
                              void* d_out, int out_size, void* d_ws, size_t ws_size,
                              hipStream_t stream) {
    const int*   target = (const int*)d_in[0];
    const float* emb    = (const float*)d_in[1];
    float*       out    = (float*)d_out;

    dim3 grid(BATCH / 2);
    dim3 block(256);
    embbag_sliced_kernel<<<grid, block, 0, stream>>>(target, emb, out);
}